// Round 3
// baseline (563.420 us; speedup 1.0000x reference)
//
#include <hip/hip_runtime.h>
#include <hip/hip_bf16.h>

// SoftmaxSetAttention: out = softmax(Q K^T / sqrt(D) + log(mult)) V
// B=2 H=16 LQ=LK=2048 D=128, fp32 in/out, bf16 MFMA compute.
// Round 3: S^T trick (in-lane softmax, b64 P writes), register-prefetch
// staging pipeline, XCD-aware block swizzle.
constexpr int B_  = 2;
constexpr int H_  = 16;
constexpr int LQ_ = 2048;
constexpr int LK_ = 2048;
constexpr int D_  = 128;

constexpr int BM = 128;  // q rows per block (4 waves x 32)
constexpr int BN = 64;   // keys per K-iteration

// log2(e) / sqrt(128): folded into Q -> pure exp2 softmax
constexpr float SCALE_LOG2E = 0.12751649734586414f;

typedef short s16x4 __attribute__((ext_vector_type(4)));
typedef short s16x8 __attribute__((ext_vector_type(8)));
typedef float f32x4 __attribute__((ext_vector_type(4)));

#define MFMA16 __builtin_amdgcn_mfma_f32_16x16x32_bf16

#if __has_builtin(__builtin_amdgcn_exp2f)
#define EXP2(x) __builtin_amdgcn_exp2f(x)
#else
#define EXP2(x) exp2f(x)
#endif
#if __has_builtin(__builtin_amdgcn_logf)
#define LOG2(x) __builtin_amdgcn_logf(x)   // v_log_f32 computes log2
#else
#define LOG2(x) log2f(x)
#endif

static __device__ __forceinline__ int pk2bf(float a, float b) {
  float2 t{a, b};
  __hip_bfloat162 h = __float22bfloat162_rn(t);
  return *reinterpret_cast<int*>(&h);
}

__global__ __launch_bounds__(256, 2)
void attn_fwd(const float* __restrict__ qg, const float* __restrict__ kg,
              const float* __restrict__ vg, const int* __restrict__ multg,
              float* __restrict__ outg) {
  // K: 64 keys x 128 d, stride 128, 16B blocks XOR-swizzled by (row&15)
  __shared__ alignas(16) short Ksh[64 * 128];   // 16384 B
  // V^T: 128 d x 64 keys, stride 64, 16B blocks XOR-swizzled by ((d>>1)&7)
  __shared__ alignas(16) short Vsh[128 * 64];   // 16384 B
  // P: 128 q x 64 keys, stride 64, 16B blocks XOR-swizzled by (row&7)
  __shared__ alignas(16) short Psh[128 * 64];   // 16384 B
  __shared__ alignas(16) float biasSh[LK_];     //  8192 B
  __shared__ alignas(16) float xferSh[4][2][16];//   512 B  -> 57856 B total

  const int tid  = threadIdx.x;
  const int w    = tid >> 6;        // wave 0..3
  const int lane = tid & 63;
  const int c    = lane & 15;       // MFMA free index
  const int qd   = lane >> 4;       // quad 0..3

  // XCD-aware swizzle: round-robin dispatch -> XCD = L%8; give each XCD
  // 4 exclusive bh (K/V tiles stay in that XCD's L2).
  const int L   = blockIdx.y * gridDim.x + blockIdx.x;   // 0..511
  const int k8  = L >> 3;
  const int qb  = k8 & 15;
  const int bh  = (L & 7) * 4 + (k8 >> 4);
  const int b   = bh >> 4;

  const float* qptr = qg + (size_t)bh * LQ_ * D_;
  const float* kptr = kg + (size_t)bh * LK_ * D_;
  const float* vptr = vg + (size_t)bh * LK_ * D_;
  float*       optr = outg + (size_t)bh * LQ_ * D_;
  const int*   mptr = multg + b * LK_;

  // ---- bias = log2(multiplicity) into LDS (once) ----
  for (int i = tid; i < LK_; i += 256)
    biasSh[i] = LOG2((float)mptr[i]);

  // ---- Q fragments (B-operand layout: n=q-row, k=d), scale folded in ----
  const int q0 = qb * BM + w * 32;
  s16x8 qf[2][4];
#pragma unroll
  for (int qs = 0; qs < 2; ++qs) {
    const float* qrow = qptr + (size_t)(q0 + qs * 16 + c) * D_ + qd * 8;
#pragma unroll
    for (int kf = 0; kf < 4; ++kf) {
      float4 a  = *(const float4*)(qrow + kf * 32);
      float4 bq = *(const float4*)(qrow + kf * 32 + 4);
      int4 t;
      t.x = pk2bf(a.x * SCALE_LOG2E, a.y * SCALE_LOG2E);
      t.y = pk2bf(a.z * SCALE_LOG2E, a.w * SCALE_LOG2E);
      t.z = pk2bf(bq.x * SCALE_LOG2E, bq.y * SCALE_LOG2E);
      t.w = pk2bf(bq.z * SCALE_LOG2E, bq.w * SCALE_LOG2E);
      qf[qs][kf] = *(s16x8*)&t;
    }
  }

  // ---- accumulators / online-softmax state (per lane: one row = c per qs) --
  f32x4 o[2][8];
  float m_r[2], l_r[2];
#pragma unroll
  for (int qs = 0; qs < 2; ++qs) {
#pragma unroll
    for (int dt = 0; dt < 8; ++dt) o[qs][dt] = (f32x4){0.f, 0.f, 0.f, 0.f};
    m_r[qs] = -INFINITY; l_r[qs] = 0.f;
  }

  // ---- staging prefetch registers ----
  float4 kreg[8];
  float2 vreg[16];

  auto loadKV = [&](int kt) {
    const int k0 = kt * BN;
#pragma unroll
    for (int i = 0; i < 8; ++i) {
      int f4  = tid + i * 256;
      int row = f4 >> 5;
      int d0  = (f4 & 31) * 4;
      kreg[i] = *(const float4*)(kptr + (size_t)(k0 + row) * D_ + d0);
    }
#pragma unroll
    for (int r = 0; r < 2; ++r) {
      const float* vrow = vptr + (size_t)(k0 + (w + r * 4) * 8) * D_ + 2 * lane;
#pragma unroll
      for (int j = 0; j < 8; ++j)
        vreg[r * 8 + j] = *(const float2*)(vrow + (size_t)j * D_);
    }
  };

  auto storeKV = [&]() {
#pragma unroll
    for (int i = 0; i < 8; ++i) {
      int f4  = tid + i * 256;
      int row = f4 >> 5;
      int d0  = (f4 & 31) * 4;
      int2 pk;
      pk.x = pk2bf(kreg[i].x, kreg[i].y);
      pk.y = pk2bf(kreg[i].z, kreg[i].w);
      int pos = (d0 >> 3) ^ (row & 15);
      *(int2*)&Ksh[row * 128 + pos * 8 + (d0 & 4)] = pk;
    }
#pragma unroll
    for (int r = 0; r < 2; ++r) {
      int kgrp = w + r * 4;
#pragma unroll
      for (int half = 0; half < 2; ++half) {
        float v[8];
#pragma unroll
        for (int j = 0; j < 8; ++j)
          v[j] = half ? vreg[r * 8 + j].y : vreg[r * 8 + j].x;
        int4 t;
        t.x = pk2bf(v[0], v[1]); t.y = pk2bf(v[2], v[3]);
        t.z = pk2bf(v[4], v[5]); t.w = pk2bf(v[6], v[7]);
        int d   = 2 * lane + half;
        int pos = kgrp ^ (lane & 7);
        *(int4*)&Vsh[d * 64 + pos * 8] = t;
      }
    }
  };

  loadKV(0);
  storeKV();
  __syncthreads();

  for (int kt = 0; kt < LK_ / BN; ++kt) {
    const int k0 = kt * BN;
    const bool last = (kt == LK_ / BN - 1);
    if (!last) loadKV(kt + 1);   // prefetch into regs; waits land in storeKV

    // ---- S^T = K Q^T : C-layout row = key(qd*4+reg), col = q-row(c) ----
    f32x4 St[2][4];
#pragma unroll
    for (int qs = 0; qs < 2; ++qs)
#pragma unroll
      for (int ct = 0; ct < 4; ++ct) St[qs][ct] = (f32x4){0.f, 0.f, 0.f, 0.f};

#pragma unroll
    for (int ct = 0; ct < 4; ++ct) {
      const short* kb = &Ksh[(ct * 16 + c) * 128];
#pragma unroll
      for (int kf = 0; kf < 4; ++kf) {
        s16x8 kfr = *(const s16x8*)&kb[((kf * 4 + qd) ^ c) * 8];
        St[0][ct] = MFMA16(kfr, qf[0][kf], St[0][ct], 0, 0, 0);
        St[1][ct] = MFMA16(kfr, qf[1][kf], St[1][ct], 0, 0, 0);
      }
    }

    // ---- bias (per lane: keys ct*16+qd*4+{0..3}) ----
    float bvf[4][4];
#pragma unroll
    for (int ct = 0; ct < 4; ++ct) {
      float4 bv = *(const float4*)&biasSh[k0 + ct * 16 + qd * 4];
      bvf[ct][0] = bv.x; bvf[ct][1] = bv.y; bvf[ct][2] = bv.z; bvf[ct][3] = bv.w;
    }

    // ---- online softmax: mostly in-lane; P^T written with b64 stores ----
#pragma unroll
    for (int qs = 0; qs < 2; ++qs) {
      float x[4][4];
#pragma unroll
      for (int ct = 0; ct < 4; ++ct)
#pragma unroll
        for (int reg = 0; reg < 4; ++reg)
          x[ct][reg] = St[qs][ct][reg] + bvf[ct][reg];

      float mx = x[0][0];
#pragma unroll
      for (int ct = 0; ct < 4; ++ct)
#pragma unroll
        for (int reg = 0; reg < 4; ++reg) mx = fmaxf(mx, x[ct][reg]);
      mx = fmaxf(mx, __shfl_xor(mx, 16));
      mx = fmaxf(mx, __shfl_xor(mx, 32));

      float mn    = fmaxf(m_r[qs], mx);
      float alpha = EXP2(m_r[qs] - mn);
      m_r[qs] = mn;

      float rs = 0.f;
#pragma unroll
      for (int ct = 0; ct < 4; ++ct)
#pragma unroll
        for (int reg = 0; reg < 4; ++reg) {
          float p = EXP2(x[ct][reg] - mn);
          x[ct][reg] = p;
          rs += p;
        }
      rs += __shfl_xor(rs, 16);
      rs += __shfl_xor(rs, 32);
      l_r[qs] = l_r[qs] * alpha + rs;

      // P[q=c][4 consecutive keys] -> b64 write, swizzled
      const int pr = w * 32 + qs * 16 + c;
#pragma unroll
      for (int ct = 0; ct < 4; ++ct) {
        int2 pk;
        pk.x = pk2bf(x[ct][0], x[ct][1]);
        pk.y = pk2bf(x[ct][2], x[ct][3]);
        int pos = (ct * 2 + (qd >> 1)) ^ (pr & 7);
        *(int2*)&Psh[pr * 64 + pos * 8 + (qd & 1) * 4] = pk;
      }

      if (qd == 0) xferSh[w][qs][c] = alpha;
    }

    // ---- rescale O by alpha (bounced to O's row layout) ----
#pragma unroll
    for (int qs = 0; qs < 2; ++qs) {
      float4 a4 = *(const float4*)&xferSh[w][qs][qd * 4];
      float ar[4] = {a4.x, a4.y, a4.z, a4.w};
#pragma unroll
      for (int dt = 0; dt < 8; ++dt)
#pragma unroll
        for (int reg = 0; reg < 4; ++reg) o[qs][dt][reg] *= ar[reg];
    }

    // ---- O += P V ----
    s16x8 pf[2][2];
#pragma unroll
    for (int qs = 0; qs < 2; ++qs) {
      const int pr = w * 32 + qs * 16 + c;
#pragma unroll
      for (int kf = 0; kf < 2; ++kf) {
        int pos = (kf * 4 + qd) ^ (pr & 7);
        pf[qs][kf] = *(const s16x8*)&Psh[pr * 64 + pos * 8];
      }
    }
#pragma unroll
    for (int dt = 0; dt < 8; ++dt) {
      int d = dt * 16 + c;
      const short* vb = &Vsh[d * 64];
      s16x8 vf[2];
#pragma unroll
      for (int kf = 0; kf < 2; ++kf)
        vf[kf] = *(const s16x8*)&vb[((kf * 4 + qd) ^ ((d >> 1) & 7)) * 8];
#pragma unroll
      for (int qs = 0; qs < 2; ++qs)
#pragma unroll
        for (int kf = 0; kf < 2; ++kf)
          o[qs][dt] = MFMA16(pf[qs][kf], vf[kf], o[qs][dt], 0, 0, 0);
    }

    if (!last) {
      __syncthreads();   // everyone done reading Ksh/Vsh(kt)
      storeKV();         // write tile kt+1 (vmcnt waits here, hidden by compute)
      __syncthreads();   // tile kt+1 visible
    }
  }

  // ---- epilogue: normalize (l bounced to O's row layout) and store ----
  if (qd == 0) { xferSh[w][0][c] = l_r[0]; xferSh[w][1][c] = l_r[1]; }
#pragma unroll
  for (int qs = 0; qs < 2; ++qs) {
    float4 l4 = *(const float4*)&xferSh[w][qs][qd * 4];
    float lr[4] = {l4.x, l4.y, l4.z, l4.w};
#pragma unroll
    for (int reg = 0; reg < 4; ++reg) {
      float inv = 1.0f / lr[reg];
      int row = q0 + qs * 16 + qd * 4 + reg;
      float* orow = optr + (size_t)row * D_ + c;
#pragma unroll
      for (int dt = 0; dt < 8; ++dt) orow[dt * 16] = o[qs][dt][reg] * inv;
    }
  }
}

extern "C" void kernel_launch(void* const* d_in, const int* in_sizes, int n_in,
                              void* d_out, int out_size, void* d_ws, size_t ws_size,
                              hipStream_t stream) {
  const float* q = (const float*)d_in[0];
  const float* k = (const float*)d_in[1];
  const float* v = (const float*)d_in[2];
  const int* mult = (const int*)d_in[3];
  float* out = (float*)d_out;

  dim3 grid(LQ_ / BM, B_ * H_);
  dim3 block(256);
  attn_fwd<<<grid, block, 0, stream>>>(q, k, v, mult, out);
}

// Round 4
// 244.405 us; speedup vs baseline: 2.3053x; 2.3053x over previous
//
#include <hip/hip_runtime.h>
#include <hip/hip_bf16.h>

// SoftmaxSetAttention: out = softmax(Q K^T / sqrt(D) + log(mult)) V
// B=2 H=16 LQ=LK=2048 D=128, fp32 in/out, bf16 MFMA compute.
// Round 4: round-3 algorithm (S^T in-lane softmax, b64 P writes, XCD swizzle)
// with inline staging (no long-lived prefetch registers -> no scratch spills).
constexpr int B_  = 2;
constexpr int H_  = 16;
constexpr int LQ_ = 2048;
constexpr int LK_ = 2048;
constexpr int D_  = 128;

constexpr int BM = 128;  // q rows per block (4 waves x 32)
constexpr int BN = 64;   // keys per K-iteration

// log2(e) / sqrt(128): folded into Q -> pure exp2 softmax
constexpr float SCALE_LOG2E = 0.12751649734586414f;

typedef short s16x4 __attribute__((ext_vector_type(4)));
typedef short s16x8 __attribute__((ext_vector_type(8)));
typedef float f32x4 __attribute__((ext_vector_type(4)));

#define MFMA16 __builtin_amdgcn_mfma_f32_16x16x32_bf16

#if __has_builtin(__builtin_amdgcn_exp2f)
#define EXP2(x) __builtin_amdgcn_exp2f(x)
#else
#define EXP2(x) exp2f(x)
#endif
#if __has_builtin(__builtin_amdgcn_logf)
#define LOG2(x) __builtin_amdgcn_logf(x)   // v_log_f32 computes log2
#else
#define LOG2(x) log2f(x)
#endif

static __device__ __forceinline__ int pk2bf(float a, float b) {
  float2 t{a, b};
  __hip_bfloat162 h = __float22bfloat162_rn(t);
  return *reinterpret_cast<int*>(&h);
}

__global__ __launch_bounds__(256, 2)
void attn_fwd(const float* __restrict__ qg, const float* __restrict__ kg,
              const float* __restrict__ vg, const int* __restrict__ multg,
              float* __restrict__ outg) {
  // K: 64 keys x 128 d, stride 128, 16B blocks XOR-swizzled by (row&15)
  __shared__ alignas(16) short Ksh[64 * 128];   // 16384 B
  // V^T: 128 d x 64 keys, stride 64, 16B blocks XOR-swizzled by ((d>>1)&7)
  __shared__ alignas(16) short Vsh[128 * 64];   // 16384 B
  // P: 128 q x 64 keys, stride 64, 16B blocks XOR-swizzled by (row&7)
  __shared__ alignas(16) short Psh[128 * 64];   // 16384 B
  __shared__ alignas(16) float biasSh[LK_];     //  8192 B
  __shared__ alignas(16) float xferSh[4][2][16];//   512 B  -> 57856 B total

  const int tid  = threadIdx.x;
  const int w    = tid >> 6;        // wave 0..3
  const int lane = tid & 63;
  const int c    = lane & 15;       // MFMA free index
  const int qd   = lane >> 4;       // quad 0..3

  // XCD-aware swizzle: round-robin dispatch -> XCD = L%8; give each XCD
  // 4 exclusive bh (K/V tiles stay in that XCD's L2).
  const int L   = blockIdx.y * gridDim.x + blockIdx.x;   // 0..511
  const int k8  = L >> 3;
  const int qb  = k8 & 15;
  const int bh  = (L & 7) * 4 + (k8 >> 4);
  const int b   = bh >> 4;

  const float* qptr = qg + (size_t)bh * LQ_ * D_;
  const float* kptr = kg + (size_t)bh * LK_ * D_;
  const float* vptr = vg + (size_t)bh * LK_ * D_;
  float*       optr = outg + (size_t)bh * LQ_ * D_;
  const int*   mptr = multg + b * LK_;

  // ---- bias = log2(multiplicity) into LDS (once) ----
  for (int i = tid; i < LK_; i += 256)
    biasSh[i] = LOG2((float)mptr[i]);

  // ---- Q fragments (B-operand layout: n=q-row, k=d), scale folded in ----
  const int q0 = qb * BM + w * 32;
  s16x8 qf[2][4];
#pragma unroll
  for (int qs = 0; qs < 2; ++qs) {
    const float* qrow = qptr + (size_t)(q0 + qs * 16 + c) * D_ + qd * 8;
#pragma unroll
    for (int kf = 0; kf < 4; ++kf) {
      float4 a  = *(const float4*)(qrow + kf * 32);
      float4 bq = *(const float4*)(qrow + kf * 32 + 4);
      int4 t;
      t.x = pk2bf(a.x * SCALE_LOG2E, a.y * SCALE_LOG2E);
      t.y = pk2bf(a.z * SCALE_LOG2E, a.w * SCALE_LOG2E);
      t.z = pk2bf(bq.x * SCALE_LOG2E, bq.y * SCALE_LOG2E);
      t.w = pk2bf(bq.z * SCALE_LOG2E, bq.w * SCALE_LOG2E);
      qf[qs][kf] = *(s16x8*)&t;
    }
  }

  // ---- accumulators / online-softmax state (per lane: one q-row = c) ----
  f32x4 o[2][8];
  float m_r[2], l_r[2];
#pragma unroll
  for (int qs = 0; qs < 2; ++qs) {
#pragma unroll
    for (int dt = 0; dt < 8; ++dt) o[qs][dt] = (f32x4){0.f, 0.f, 0.f, 0.f};
    m_r[qs] = -INFINITY; l_r[qs] = 0.f;
  }

  for (int kt = 0; kt < LK_ / BN; ++kt) {
    const int k0 = kt * BN;
    __syncthreads();  // previous iteration's frag reads done (and biasSh ready)

    // ---- stage K tile (64 keys x 128 d) -> bf16 LDS, swizzled ----
#pragma unroll
    for (int i = 0; i < 8; ++i) {
      int f4  = tid + i * 256;       // 0..2047 float4s
      int row = f4 >> 5;             // key 0..63
      int d0  = (f4 & 31) * 4;       // 0..124
      float4 a = *(const float4*)(kptr + (size_t)(k0 + row) * D_ + d0);
      int2 pk;
      pk.x = pk2bf(a.x, a.y);
      pk.y = pk2bf(a.z, a.w);
      int pos = (d0 >> 3) ^ (row & 15);           // 16B-block swizzle
      *(int2*)&Ksh[row * 128 + pos * 8 + (d0 & 4)] = pk;
    }

    // ---- stage V tile transposed (d-major), swizzled 8-key blocks ----
#pragma unroll
    for (int r = 0; r < 2; ++r) {
      int kgrp = w + r * 4;          // 8-key group 0..7
      float2 f2v[8];
      const float* vrow = vptr + (size_t)(k0 + kgrp * 8) * D_ + 2 * lane;
#pragma unroll
      for (int j = 0; j < 8; ++j)
        f2v[j] = *(const float2*)(vrow + (size_t)j * D_);
#pragma unroll
      for (int half = 0; half < 2; ++half) {
        int4 t;
        t.x = pk2bf(half ? f2v[0].y : f2v[0].x, half ? f2v[1].y : f2v[1].x);
        t.y = pk2bf(half ? f2v[2].y : f2v[2].x, half ? f2v[3].y : f2v[3].x);
        t.z = pk2bf(half ? f2v[4].y : f2v[4].x, half ? f2v[5].y : f2v[5].x);
        t.w = pk2bf(half ? f2v[6].y : f2v[6].x, half ? f2v[7].y : f2v[7].x);
        int d   = 2 * lane + half;
        int pos = kgrp ^ (lane & 7);  // == kgrp ^ ((d>>1)&7)
        *(int4*)&Vsh[d * 64 + pos * 8] = t;
      }
    }
    __syncthreads();

    // ---- S^T = K Q^T : C-layout row = key(qd*4+reg), col = q-row(c) ----
    f32x4 St[2][4];
#pragma unroll
    for (int qs = 0; qs < 2; ++qs)
#pragma unroll
      for (int ct = 0; ct < 4; ++ct) St[qs][ct] = (f32x4){0.f, 0.f, 0.f, 0.f};

#pragma unroll
    for (int ct = 0; ct < 4; ++ct) {
      const short* kb = &Ksh[(ct * 16 + c) * 128];
#pragma unroll
      for (int kf = 0; kf < 4; ++kf) {
        s16x8 kfr = *(const s16x8*)&kb[((kf * 4 + qd) ^ c) * 8];
        St[0][ct] = MFMA16(kfr, qf[0][kf], St[0][ct], 0, 0, 0);
        St[1][ct] = MFMA16(kfr, qf[1][kf], St[1][ct], 0, 0, 0);
      }
    }

    // ---- bias (per lane: keys ct*16+qd*4+{0..3}) ----
    float bvf[4][4];
#pragma unroll
    for (int ct = 0; ct < 4; ++ct) {
      float4 bv = *(const float4*)&biasSh[k0 + ct * 16 + qd * 4];
      bvf[ct][0] = bv.x; bvf[ct][1] = bv.y; bvf[ct][2] = bv.z; bvf[ct][3] = bv.w;
    }

    // ---- online softmax: in-lane + 2 shuffles; P^T written as b64 ----
#pragma unroll
    for (int qs = 0; qs < 2; ++qs) {
      float x[4][4];
#pragma unroll
      for (int ct = 0; ct < 4; ++ct)
#pragma unroll
        for (int reg = 0; reg < 4; ++reg)
          x[ct][reg] = St[qs][ct][reg] + bvf[ct][reg];

      float mx = x[0][0];
#pragma unroll
      for (int ct = 0; ct < 4; ++ct)
#pragma unroll
        for (int reg = 0; reg < 4; ++reg) mx = fmaxf(mx, x[ct][reg]);
      mx = fmaxf(mx, __shfl_xor(mx, 16));
      mx = fmaxf(mx, __shfl_xor(mx, 32));

      float mn    = fmaxf(m_r[qs], mx);
      float alpha = EXP2(m_r[qs] - mn);
      m_r[qs] = mn;

      float rs = 0.f;
#pragma unroll
      for (int ct = 0; ct < 4; ++ct)
#pragma unroll
        for (int reg = 0; reg < 4; ++reg) {
          float p = EXP2(x[ct][reg] - mn);
          x[ct][reg] = p;
          rs += p;
        }
      rs += __shfl_xor(rs, 16);
      rs += __shfl_xor(rs, 32);
      l_r[qs] = l_r[qs] * alpha + rs;

      // P[q=c][4 consecutive keys] -> b64 write, swizzled
      const int pr = w * 32 + qs * 16 + c;
#pragma unroll
      for (int ct = 0; ct < 4; ++ct) {
        int2 pk;
        pk.x = pk2bf(x[ct][0], x[ct][1]);
        pk.y = pk2bf(x[ct][2], x[ct][3]);
        int pos = (ct * 2 + (qd >> 1)) ^ (pr & 7);
        *(int2*)&Psh[pr * 64 + pos * 8 + (qd & 1) * 4] = pk;
      }

      if (qd == 0) xferSh[w][qs][c] = alpha;
    }

    // ---- rescale O by alpha (bounced to O's row layout) ----
#pragma unroll
    for (int qs = 0; qs < 2; ++qs) {
      float4 a4 = *(const float4*)&xferSh[w][qs][qd * 4];
      float ar[4] = {a4.x, a4.y, a4.z, a4.w};
#pragma unroll
      for (int dt = 0; dt < 8; ++dt)
#pragma unroll
        for (int reg = 0; reg < 4; ++reg) o[qs][dt][reg] *= ar[reg];
    }

    // ---- O += P V ----
    s16x8 pf[2][2];
#pragma unroll
    for (int qs = 0; qs < 2; ++qs) {
      const int pr = w * 32 + qs * 16 + c;
#pragma unroll
      for (int kf = 0; kf < 2; ++kf) {
        int pos = (kf * 4 + qd) ^ (pr & 7);
        pf[qs][kf] = *(const s16x8*)&Psh[pr * 64 + pos * 8];
      }
    }
#pragma unroll
    for (int dt = 0; dt < 8; ++dt) {
      int d = dt * 16 + c;
      const short* vb = &Vsh[d * 64];
      s16x8 vf[2];
#pragma unroll
      for (int kf = 0; kf < 2; ++kf)
        vf[kf] = *(const s16x8*)&vb[((kf * 4 + qd) ^ ((d >> 1) & 7)) * 8];
#pragma unroll
      for (int qs = 0; qs < 2; ++qs)
#pragma unroll
        for (int kf = 0; kf < 2; ++kf)
          o[qs][dt] = MFMA16(pf[qs][kf], vf[kf], o[qs][dt], 0, 0, 0);
    }
  }

  // ---- epilogue: normalize (l bounced to O's row layout) and store ----
  if (qd == 0) { xferSh[w][0][c] = l_r[0]; xferSh[w][1][c] = l_r[1]; }
#pragma unroll
  for (int qs = 0; qs < 2; ++qs) {
    float4 l4 = *(const float4*)&xferSh[w][qs][qd * 4];
    float lr[4] = {l4.x, l4.y, l4.z, l4.w};
#pragma unroll
    for (int reg = 0; reg < 4; ++reg) {
      float inv = 1.0f / lr[reg];
      int row = q0 + qs * 16 + qd * 4 + reg;
      float* orow = optr + (size_t)row * D_ + c;
#pragma unroll
      for (int dt = 0; dt < 8; ++dt) orow[dt * 16] = o[qs][dt][reg] * inv;
    }
  }
}

extern "C" void kernel_launch(void* const* d_in, const int* in_sizes, int n_in,
                              void* d_out, int out_size, void* d_ws, size_t ws_size,
                              hipStream_t stream) {
  const float* q = (const float*)d_in[0];
  const float* k = (const float*)d_in[1];
  const float* v = (const float*)d_in[2];
  const int* mult = (const int*)d_in[3];
  float* out = (float*)d_out;

  dim3 grid(LQ_ / BM, B_ * H_);
  dim3 block(256);
  attn_fwd<<<grid, block, 0, stream>>>(q, k, v, mult, out);
}

// Round 6
// 231.474 us; speedup vs baseline: 2.4341x; 1.0559x over previous
//
#include <hip/hip_runtime.h>
#include <hip/hip_bf16.h>

// SoftmaxSetAttention: out = softmax(Q K^T / sqrt(D) + log(mult)) V
// B=2 H=16 LQ=LK=2048 D=128, fp32 in/out, bf16 MFMA compute.
// Round 6: round-5 pipeline (prep kernel pre-converts K/V to bf16 tiles with
// the LDS swizzle pre-baked, V transposed d-major; main loop DMA-stages via
// global_load_lds width-16 into double-buffered LDS, one barrier/iter) with
// the bias-fill bug fixed (prep wrote only half of wsBias).
constexpr int B_  = 2;
constexpr int H_  = 16;
constexpr int LQ_ = 2048;
constexpr int LK_ = 2048;
constexpr int D_  = 128;

constexpr int BM = 128;   // q rows per block (4 waves x 32)
constexpr int BN = 64;    // keys per K-iteration
constexpr int NT = LK_ / BN;              // 32 tiles per bh
constexpr int TILE_SH = 64 * 128;         // shorts per K or V tile (16 KB)

// log2(e) / sqrt(128): folded into Q -> pure exp2 softmax
constexpr float SCALE_LOG2E = 0.12751649734586414f;

typedef short s16x4 __attribute__((ext_vector_type(4)));
typedef short s16x8 __attribute__((ext_vector_type(8)));
typedef float f32x4 __attribute__((ext_vector_type(4)));

#define MFMA16 __builtin_amdgcn_mfma_f32_16x16x32_bf16

#if __has_builtin(__builtin_amdgcn_exp2f)
#define EXP2(x) __builtin_amdgcn_exp2f(x)
#else
#define EXP2(x) exp2f(x)
#endif
#if __has_builtin(__builtin_amdgcn_logf)
#define LOG2(x) __builtin_amdgcn_logf(x)   // v_log_f32 computes log2
#else
#define LOG2(x) log2f(x)
#endif

static __device__ __forceinline__ int pk2bf(float a, float b) {
  float2 t{a, b};
  __hip_bfloat162 h = __float22bfloat162_rn(t);
  return *reinterpret_cast<int*>(&h);
}

static __device__ __forceinline__ void dma16(const short* g, short* l) {
  __builtin_amdgcn_global_load_lds(
      (const __attribute__((address_space(1))) void*)g,
      (__attribute__((address_space(3))) void*)l, 16, 0, 0);
}

// ---------------- prep: K -> bf16 swizzled tiles, V -> bf16 transposed ------
// wsK tile layout (shorts): row*128 + (blk^(row&15))*8 + (d&7), blk=d>>3
// wsV tile layout (shorts): d*64 + (kgrp^((d>>1)&7))*8 + (key&7), kgrp=key>>3
__global__ __launch_bounds__(256)
void prep(const float* __restrict__ kg, const float* __restrict__ vg,
          const int* __restrict__ multg, short* __restrict__ wsK,
          short* __restrict__ wsV, float* __restrict__ wsBias) {
  __shared__ float tileF[64 * 133];
  const int tid = threadIdx.x;
  const int wg  = blockIdx.x;          // 0..1023 = bh*32 + kt
  const float* kp = kg + (size_t)wg * 64 * 128;
  const float* vp = vg + (size_t)wg * 64 * 128;
  short* wk = wsK + (size_t)wg * TILE_SH;
  short* wv = wsV + (size_t)wg * TILE_SH;

  // ---- K convert (no transpose) ----
#pragma unroll
  for (int i = 0; i < 4; ++i) {
    int idx = tid + i * 256;           // 0..1023
    int row = idx >> 4, blk = idx & 15;
    const float* src = kp + row * 128 + blk * 8;
    float4 a = *(const float4*)src;
    float4 c4 = *(const float4*)(src + 4);
    int4 t;
    t.x = pk2bf(a.x, a.y);  t.y = pk2bf(a.z, a.w);
    t.z = pk2bf(c4.x, c4.y); t.w = pk2bf(c4.z, c4.w);
    int pos = blk ^ (row & 15);
    *(int4*)&wk[row * 128 + pos * 8] = t;
  }

  // ---- V transpose through LDS ----
#pragma unroll
  for (int i = 0; i < 8; ++i) {
    int idx = tid + i * 256;           // 0..2047
    int key = idx >> 5, d0 = (idx & 31) * 4;
    float4 a = *(const float4*)(vp + key * 128 + d0);
    float* dst = &tileF[key * 133 + d0];
    dst[0] = a.x; dst[1] = a.y; dst[2] = a.z; dst[3] = a.w;
  }
  __syncthreads();
#pragma unroll
  for (int i = 0; i < 4; ++i) {
    int idx = tid + i * 256;           // 0..1023
    int d = idx >> 3, kgrp = idx & 7;
    float v[8];
#pragma unroll
    for (int j = 0; j < 8; ++j) v[j] = tileF[(kgrp * 8 + j) * 133 + d];
    int4 t;
    t.x = pk2bf(v[0], v[1]); t.y = pk2bf(v[2], v[3]);
    t.z = pk2bf(v[4], v[5]); t.w = pk2bf(v[6], v[7]);
    int pos = kgrp ^ ((d >> 1) & 7);
    *(int4*)&wv[d * 64 + pos * 8] = t;
  }

  // ---- bias = log2(mult): 8 blocks x 512 entries (FIX: was half-written) ----
  if (wg < 8) {
    int b = wg >> 2;
    for (int j = tid; j < 512; j += 256) {
      int i0 = (wg & 3) * 512 + j;
      wsBias[b * LK_ + i0] = LOG2((float)multg[b * LK_ + i0]);
    }
  }
}

// ---------------- main attention kernel -------------------------------------
__global__ __launch_bounds__(256, 2)
void attn_fwd(const float* __restrict__ qg, const short* __restrict__ wsK,
              const short* __restrict__ wsV, const float* __restrict__ wsBias,
              float* __restrict__ outg) {
  __shared__ alignas(16) short Kbuf[2][TILE_SH];  // 2 x 16 KB
  __shared__ alignas(16) short Vbuf[2][TILE_SH];  // 2 x 16 KB
  __shared__ alignas(16) short Psh[128 * 64];     // 16 KB -> 80 KB total

  const int tid  = threadIdx.x;
  const int w    = tid >> 6;        // wave 0..3
  const int lane = tid & 63;
  const int c    = lane & 15;       // MFMA free index
  const int qd   = lane >> 4;       // quad 0..3

  // XCD-aware swizzle: round-robin dispatch -> XCD = L%8; each XCD owns 4 bh.
  const int L   = blockIdx.y * gridDim.x + blockIdx.x;   // 0..511
  const int k8  = L >> 3;
  const int qb  = k8 & 15;
  const int bh  = (L & 7) * 4 + (k8 >> 4);
  const int b   = bh >> 4;

  const float* qptr = qg + (size_t)bh * LQ_ * D_;
  float*       optr = outg + (size_t)bh * LQ_ * D_;
  const short* kws  = wsK + (size_t)bh * NT * TILE_SH;
  const short* vws  = wsV + (size_t)bh * NT * TILE_SH;
  const float* bias = wsBias + b * LK_;

  // ---- Q fragments (B-operand layout: n=q-row, k=d), scale folded in ----
  const int q0 = qb * BM + w * 32;
  s16x8 qf[2][4];
#pragma unroll
  for (int qs = 0; qs < 2; ++qs) {
    const float* qrow = qptr + (size_t)(q0 + qs * 16 + c) * D_ + qd * 8;
#pragma unroll
    for (int kf = 0; kf < 4; ++kf) {
      float4 a  = *(const float4*)(qrow + kf * 32);
      float4 bq = *(const float4*)(qrow + kf * 32 + 4);
      int4 t;
      t.x = pk2bf(a.x * SCALE_LOG2E, a.y * SCALE_LOG2E);
      t.y = pk2bf(a.z * SCALE_LOG2E, a.w * SCALE_LOG2E);
      t.z = pk2bf(bq.x * SCALE_LOG2E, bq.y * SCALE_LOG2E);
      t.w = pk2bf(bq.z * SCALE_LOG2E, bq.w * SCALE_LOG2E);
      qf[qs][kf] = *(s16x8*)&t;
    }
  }

  // ---- accumulators / online-softmax state (per lane: one q-row = c) ----
  f32x4 o[2][8];
  float m_r[2], l_r[2];
#pragma unroll
  for (int qs = 0; qs < 2; ++qs) {
#pragma unroll
    for (int dt = 0; dt < 8; ++dt) o[qs][dt] = (f32x4){0.f, 0.f, 0.f, 0.f};
    m_r[qs] = -INFINITY; l_r[qs] = 0.f;
  }

  // ---- DMA a K/V tile into LDS buffer bb (4 chunks of 1 KB per wave) ----
  auto dmaKV = [&](int kt, int bb) {
    const short* gK = kws + (size_t)kt * TILE_SH;
    const short* gV = vws + (size_t)kt * TILE_SH;
#pragma unroll
    for (int i = 0; i < 4; ++i) {
      int off = (w * 4 + i) * 512;    // shorts; +lane*8 implicit on LDS side
      dma16(gK + off + lane * 8, &Kbuf[bb][off]);
      dma16(gV + off + lane * 8, &Vbuf[bb][off]);
    }
  };

  dmaKV(0, 0);
  __syncthreads();   // vmcnt(0) drain: tile 0 resident

  for (int kt = 0; kt < NT; ++kt) {
    const int cur = kt & 1;
    if (kt + 1 < NT) dmaKV(kt + 1, cur ^ 1);   // async prefetch, drains at barrier

    // ---- bias loads (L2-hot), issued early ----
    float bvf[4][4];
#pragma unroll
    for (int ct = 0; ct < 4; ++ct) {
      float4 bv = *(const float4*)&bias[kt * BN + ct * 16 + qd * 4];
      bvf[ct][0] = bv.x; bvf[ct][1] = bv.y; bvf[ct][2] = bv.z; bvf[ct][3] = bv.w;
    }

    // ---- S^T = K Q^T : C-layout row = key(qd*4+reg), col = q-row(c) ----
    f32x4 St[2][4];
#pragma unroll
    for (int qs = 0; qs < 2; ++qs)
#pragma unroll
      for (int ct = 0; ct < 4; ++ct) St[qs][ct] = (f32x4){0.f, 0.f, 0.f, 0.f};

#pragma unroll
    for (int ct = 0; ct < 4; ++ct) {
      const short* kb = &Kbuf[cur][(ct * 16 + c) * 128];
#pragma unroll
      for (int kf = 0; kf < 4; ++kf) {
        s16x8 kfr = *(const s16x8*)&kb[((kf * 4 + qd) ^ c) * 8];
        St[0][ct] = MFMA16(kfr, qf[0][kf], St[0][ct], 0, 0, 0);
        St[1][ct] = MFMA16(kfr, qf[1][kf], St[1][ct], 0, 0, 0);
      }
    }

    // ---- online softmax: in-lane + 2 shuffles; P^T written as b64 ----
#pragma unroll
    for (int qs = 0; qs < 2; ++qs) {
      float x[4][4];
#pragma unroll
      for (int ct = 0; ct < 4; ++ct)
#pragma unroll
        for (int reg = 0; reg < 4; ++reg)
          x[ct][reg] = St[qs][ct][reg] + bvf[ct][reg];

      float mx = x[0][0];
#pragma unroll
      for (int ct = 0; ct < 4; ++ct)
#pragma unroll
        for (int reg = 0; reg < 4; ++reg) mx = fmaxf(mx, x[ct][reg]);
      mx = fmaxf(mx, __shfl_xor(mx, 16));
      mx = fmaxf(mx, __shfl_xor(mx, 32));

      float mn    = fmaxf(m_r[qs], mx);
      float alpha = EXP2(m_r[qs] - mn);
      m_r[qs] = mn;

      float rs = 0.f;
#pragma unroll
      for (int ct = 0; ct < 4; ++ct)
#pragma unroll
        for (int reg = 0; reg < 4; ++reg) {
          float p = EXP2(x[ct][reg] - mn);
          x[ct][reg] = p;
          rs += p;
        }
      rs += __shfl_xor(rs, 16);
      rs += __shfl_xor(rs, 32);
      l_r[qs] = l_r[qs] * alpha + rs;

      // P[q=c][4 consecutive keys] -> b64 write, swizzled (wave-private rows)
      const int pr = w * 32 + qs * 16 + c;
#pragma unroll
      for (int ct = 0; ct < 4; ++ct) {
        int2 pk;
        pk.x = pk2bf(x[ct][0], x[ct][1]);
        pk.y = pk2bf(x[ct][2], x[ct][3]);
        int pos = (ct * 2 + (qd >> 1)) ^ (pr & 7);
        *(int2*)&Psh[pr * 64 + pos * 8 + (qd & 1) * 4] = pk;
      }

      // rescale O by alpha: row r=qd*4+reg's alpha lives in lanes with c==r
      float ar[4];
#pragma unroll
      for (int reg = 0; reg < 4; ++reg) ar[reg] = __shfl(alpha, qd * 4 + reg);
#pragma unroll
      for (int dt = 0; dt < 8; ++dt)
#pragma unroll
        for (int reg = 0; reg < 4; ++reg) o[qs][dt][reg] *= ar[reg];
    }

    // ---- O += P V ----
    s16x8 pf[2][2];
#pragma unroll
    for (int qs = 0; qs < 2; ++qs) {
      const int pr = w * 32 + qs * 16 + c;
#pragma unroll
      for (int kf = 0; kf < 2; ++kf) {
        int pos = (kf * 4 + qd) ^ (pr & 7);
        pf[qs][kf] = *(const s16x8*)&Psh[pr * 64 + pos * 8];
      }
    }
#pragma unroll
    for (int dt = 0; dt < 8; ++dt) {
      int d = dt * 16 + c;
      const short* vb = &Vbuf[cur][d * 64];
      s16x8 vf[2];
#pragma unroll
      for (int kf = 0; kf < 2; ++kf)
        vf[kf] = *(const s16x8*)&vb[((kf * 4 + qd) ^ ((d >> 1) & 7)) * 8];
#pragma unroll
      for (int qs = 0; qs < 2; ++qs)
#pragma unroll
        for (int kf = 0; kf < 2; ++kf)
          o[qs][dt] = MFMA16(pf[qs][kf], vf[kf], o[qs][dt], 0, 0, 0);
    }

    __syncthreads();  // all waves done with Kbuf/Vbuf[cur]; DMA(kt+1) drained
  }

  // ---- epilogue: normalize (l bounced via shfl) and store ----
#pragma unroll
  for (int qs = 0; qs < 2; ++qs) {
    float lr[4];
#pragma unroll
    for (int reg = 0; reg < 4; ++reg) lr[reg] = __shfl(l_r[qs], qd * 4 + reg);
#pragma unroll
    for (int reg = 0; reg < 4; ++reg) {
      float inv = 1.0f / lr[reg];
      int row = q0 + qs * 16 + qd * 4 + reg;
      float* orow = optr + (size_t)row * D_ + c;
#pragma unroll
      for (int dt = 0; dt < 8; ++dt) orow[dt * 16] = o[qs][dt][reg] * inv;
    }
  }
}

extern "C" void kernel_launch(void* const* d_in, const int* in_sizes, int n_in,
                              void* d_out, int out_size, void* d_ws, size_t ws_size,
                              hipStream_t stream) {
  const float* q = (const float*)d_in[0];
  const float* k = (const float*)d_in[1];
  const float* v = (const float*)d_in[2];
  const int* mult = (const int*)d_in[3];
  float* out = (float*)d_out;

  // ws layout: K' bf16 tiles | V'^T bf16 tiles | bias fp32
  constexpr size_t KV_BYTES = (size_t)B_ * H_ * LK_ * D_ * 2;   // 16 MB each
  short* wsK = (short*)d_ws;
  short* wsV = (short*)((char*)d_ws + KV_BYTES);
  float* wsBias = (float*)((char*)d_ws + 2 * KV_BYTES);

  prep<<<dim3(B_ * H_ * NT), dim3(256), 0, stream>>>(k, v, mult, wsK, wsV, wsBias);

  dim3 grid(LQ_ / BM, B_ * H_);
  attn_fwd<<<grid, dim3(256), 0, stream>>>(q, wsK, wsV, wsBias, out);
}